// Round 1
// baseline (5170.160 us; speedup 1.0000x reference)
//
#include <hip/hip_runtime.h>
#include <cmath>

// ---- problem constants ----
#define Vv 32000
#define Dd 768
#define Hh 12
#define Ll 8
#define Tt 1024
#define Bb 4
#define HDd 64
#define Mm (Bb*Tt)   // 4096 token rows

typedef __bf16 bf16;
typedef __bf16 bf16x8 __attribute__((ext_vector_type(8)));
typedef float  f32x4  __attribute__((ext_vector_type(4)));

#define MFMA16(a,b,c) __builtin_amdgcn_mfma_f32_16x16x32_bf16((a),(b),(c),0,0,0)

__device__ __forceinline__ void gl_lds16(const void* g, void* l) {
  __builtin_amdgcn_global_load_lds(
      (const __attribute__((address_space(1))) void*)g,
      (__attribute__((address_space(3))) void*)l, 16, 0, 0);
}

// split fp32 into bf16 hi/lo (hi RTN; residual exact in fp32, then RTN)
__device__ __forceinline__ void split2(float x, bf16& h, bf16& l) {
  bf16 hh = (bf16)x;
  h = hh;
  l = (bf16)(x - (float)hh);
}

// ---------------- embedding: x = wte[idx] + wpe ----------------
__global__ void k_embed(const int* __restrict__ idx, const float* __restrict__ wte,
                        const float* __restrict__ wpe, float* __restrict__ x) {
  int row = blockIdx.x;            // 0..4095  (b*T + t)
  int t = row & (Tt - 1);
  int tok = idx[row];
  int c = threadIdx.x * 4;         // 192 threads * 4 = 768
  float4 a = *(const float4*)(wte + (size_t)tok*Dd + c);
  float4 b = *(const float4*)(wpe + (size_t)t*Dd + c);
  float4 o; o.x=a.x+b.x; o.y=a.y+b.y; o.z=a.z+b.z; o.w=a.w+b.w;
  *(float4*)(x + (size_t)row*Dd + c) = o;
}

// ------------- weight transpose + hi/lo split: Wt[n][k] = W[k][n] -------------
__global__ void k_wsplit(const float* __restrict__ W, bf16* __restrict__ Whi,
                         bf16* __restrict__ Wlo, int K, int N) {
  __shared__ float tile[32][33];
  int l = blockIdx.z;
  const float* Wl = W + (size_t)l*K*N;
  bf16* Hl = Whi + (size_t)l*K*N;
  bf16* Ol = Wlo + (size_t)l*K*N;
  int k0 = blockIdx.x*32, n0 = blockIdx.y*32;
  int tx = threadIdx.x, ty = threadIdx.y;   // (32, 8)
#pragma unroll
  for (int i=0;i<4;i++) tile[ty+8*i][tx] = Wl[(size_t)(k0+ty+8*i)*N + n0+tx];
  __syncthreads();
#pragma unroll
  for (int i=0;i<4;i++) {
    float v = tile[tx][ty+8*i];
    size_t o = (size_t)(n0+ty+8*i)*K + k0 + tx;
    bf16 h, lo; split2(v, h, lo);
    Hl[o] = h; Ol[o] = lo;
  }
}

// ---------------- LayerNorm -> bf16 hi/lo ----------------
__global__ void k_ln(const float* __restrict__ x, const float* __restrict__ g,
                     const float* __restrict__ bta, bf16* __restrict__ hhi,
                     bf16* __restrict__ hlo) {
  int row = blockIdx.x;
  const float* xr = x + (size_t)row*Dd;
  int t = threadIdx.x, wid = t>>6, lane = t&63;
  float v0 = xr[t], v1 = xr[t+256], v2 = xr[t+512];
  float s = v0+v1+v2;
#pragma unroll
  for (int m=1;m<64;m<<=1) s += __shfl_xor(s, m);
  __shared__ float r1[4];
  if (lane==0) r1[wid]=s;
  __syncthreads();
  s = r1[0]+r1[1]+r1[2]+r1[3];
  float mu = s * (1.0f/Dd);
  float d0=v0-mu, d1=v1-mu, d2=v2-mu;
  float q = d0*d0 + d1*d1 + d2*d2;
#pragma unroll
  for (int m=1;m<64;m<<=1) q += __shfl_xor(q, m);
  __shared__ float r2[4];
  if (lane==0) r2[wid]=q;
  __syncthreads();
  q = r2[0]+r2[1]+r2[2]+r2[3];
  float rs = 1.0f / sqrtf(q*(1.0f/Dd) + 1e-5f);
  size_t base = (size_t)row*Dd;
#pragma unroll
  for (int i=0;i<3;i++) {
    int c = t + i*256;
    float dv = (i==0?d0:(i==1?d1:d2));
    float o = dv*rs*g[c] + bta[c];
    bf16 h,lo; split2(o,h,lo);
    hhi[base+c]=h; hlo[base+c]=lo;
  }
}

// ---------------- split-precision GEMM: C = A@B (+epilogue) ----------------
// A: [M][K] bf16 hi/lo.  B stored TRANSPOSED: Bt [N][K] bf16 hi/lo.
// EPI: 0=store fp32; 1=+res store fp32; 2=+bias,gelu -> hi/lo bf16; 3=+bias+res fp32
template<int EPI>
__launch_bounds__(256)
__global__ void k_gemm(const bf16* __restrict__ Ahi, const bf16* __restrict__ Alo,
                       const bf16* __restrict__ Bhi, const bf16* __restrict__ Blo,
                       const int K, const int N,
                       float* __restrict__ Cout, const float* __restrict__ res,
                       const float* __restrict__ bias,
                       bf16* __restrict__ Ohi, bf16* __restrict__ Olo) {
  __shared__ bf16 lds[4][128*32];   // Ahi, Alo, Bhi, Blo tiles [128 rows][32 k]
  const int tid = threadIdx.x, wid = tid>>6, lane = tid&63;
  const int wr = wid>>1, wc = wid&1;
  const int m0 = blockIdx.x*128, n0 = blockIdx.y*128;
  const int rla = lane&15, kof = (lane>>4)*8;

  const bf16* gsrc;
  if      (wid==0) gsrc = Ahi + (size_t)m0*K;
  else if (wid==1) gsrc = Alo + (size_t)m0*K;
  else if (wid==2) gsrc = Bhi + (size_t)n0*K;
  else             gsrc = Blo + (size_t)n0*K;
  gsrc += (size_t)(lane>>2)*K + (lane&3)*8;
  bf16* ldsbase = &lds[wid][0];

  f32x4 acc[4][4] = {};

  for (int kt=0; kt<K; kt+=32) {
#pragma unroll
    for (int c=0;c<8;c++)
      gl_lds16(gsrc + (size_t)c*16*K + kt, ldsbase + c*512);
    __syncthreads();
    bf16x8 afh[4], afl[4], bfh[4], bfl[4];
#pragma unroll
    for (int i=0;i<4;i++) {
      int ra = wr*64 + i*16 + rla;
      afh[i] = *(const bf16x8*)&lds[0][ra*32 + kof];
      afl[i] = *(const bf16x8*)&lds[1][ra*32 + kof];
      int rb = wc*64 + i*16 + rla;
      bfh[i] = *(const bf16x8*)&lds[2][rb*32 + kof];
      bfl[i] = *(const bf16x8*)&lds[3][rb*32 + kof];
    }
#pragma unroll
    for (int mi=0;mi<4;mi++)
#pragma unroll
      for (int ni=0;ni<4;ni++) {
        f32x4 a = acc[mi][ni];
        a = MFMA16(afh[mi], bfh[ni], a);
        a = MFMA16(afh[mi], bfl[ni], a);
        a = MFMA16(afl[mi], bfh[ni], a);
        acc[mi][ni] = a;
      }
    __syncthreads();
  }

  const int orow = (lane>>4)*4;
#pragma unroll
  for (int mi=0;mi<4;mi++)
#pragma unroll
    for (int ni=0;ni<4;ni++)
#pragma unroll
      for (int r=0;r<4;r++) {
        int grow = m0 + wr*64 + mi*16 + orow + r;
        int gcol = n0 + wc*64 + ni*16 + rla;
        size_t o = (size_t)grow*N + gcol;
        float v = acc[mi][ni][r];
        if constexpr (EPI==0) {
          Cout[o] = v;
        } else if constexpr (EPI==1) {
          Cout[o] = res[o] + v;
        } else if constexpr (EPI==2) {
          v += bias[gcol];
          float gl = 0.5f*v*(1.0f + erff(v*0.70710678118654752f));
          bf16 h,lo; split2(gl,h,lo);
          Ohi[o]=h; Olo[o]=lo;
        } else {
          Cout[o] = res[o] + v + bias[gcol];
        }
      }
}

// ---------------- fused causal flash attention (split precision) ----------------
__launch_bounds__(256)
__global__ void k_attn(const float* __restrict__ qkv, bf16* __restrict__ yhi,
                       bf16* __restrict__ ylo) {
  const int qt = blockIdx.x, h = blockIdx.y, b = blockIdx.z;
  __shared__ bf16 Khi[64][72], Klo[64][72];   // [kv][hd], +8 pad kills bank conflicts
  __shared__ bf16 Vhi[64][72], Vlo[64][72];   // transposed: [hd][kv]
  __shared__ bf16 Phi[4][16][72], Plo[4][16][72];
  const int tid = threadIdx.x, wid = tid>>6, lane = tid&63;
  const int rla = lane&15, kof = (lane>>4)*8, orow = (lane>>4)*4;

  // Q fragments (softmax scale 1/8 folded in; exact power of 2)
  int qrow = qt*64 + wid*16 + rla;
  const float* qbase = qkv + (size_t)(b*Tt + qrow)*(3*Dd) + h*HDd;
  bf16x8 qh[2], ql[2];
#pragma unroll
  for (int kh=0; kh<2; kh++)
#pragma unroll
    for (int j=0;j<8;j++) {
      float v = qbase[kh*32 + kof + j] * 0.125f;
      bf16 hi_ = (bf16)v;
      qh[kh][j] = hi_;
      ql[kh][j] = (bf16)(v - (float)hi_);
    }

  f32x4 o[4] = {};
  float mrow[4], lrow[4];
#pragma unroll
  for (int r=0;r<4;r++){ mrow[r]=-INFINITY; lrow[r]=0.f; }

  for (int kv0=0; kv0 <= qt*64; kv0 += 64) {
    { // stage K (row-major) and V (transposed), split
      int row = tid>>2, c0 = (tid&3)*16;
      const float* kb = qkv + (size_t)(b*Tt + kv0 + row)*(3*Dd) + Dd + h*HDd + c0;
      const float* vb = kb + Dd;
      bf16x8 kh8[2], kl8[2];
#pragma unroll
      for (int hf=0; hf<2; hf++)
#pragma unroll
        for (int j=0;j<8;j++) {
          float v = kb[hf*8+j];
          bf16 hi_ = (bf16)v;
          kh8[hf][j] = hi_;
          kl8[hf][j] = (bf16)(v - (float)hi_);
        }
      *(bf16x8*)&Khi[row][c0]   = kh8[0];
      *(bf16x8*)&Khi[row][c0+8] = kh8[1];
      *(bf16x8*)&Klo[row][c0]   = kl8[0];
      *(bf16x8*)&Klo[row][c0+8] = kl8[1];
#pragma unroll
      for (int j=0;j<16;j++) {
        float v = vb[j];
        bf16 hi_ = (bf16)v;
        Vhi[c0+j][row] = hi_;
        Vlo[c0+j][row] = (bf16)(v - (float)hi_);
      }
    }
    __syncthreads();

    // S = (Q/8) K^T, split precision
    f32x4 sf[4];
#pragma unroll
    for (int nf=0;nf<4;nf++) {
      f32x4 s = {};
      bf16x8 kh0 = *(const bf16x8*)&Khi[nf*16+rla][kof];
      bf16x8 kl0 = *(const bf16x8*)&Klo[nf*16+rla][kof];
      bf16x8 kh1 = *(const bf16x8*)&Khi[nf*16+rla][32+kof];
      bf16x8 kl1 = *(const bf16x8*)&Klo[nf*16+rla][32+kof];
      s = MFMA16(qh[0], kh0, s);
      s = MFMA16(qh[0], kl0, s);
      s = MFMA16(ql[0], kh0, s);
      s = MFMA16(qh[1], kh1, s);
      s = MFMA16(qh[1], kl1, s);
      s = MFMA16(ql[1], kh1, s);
      sf[nf] = s;
    }
    if (kv0 == qt*64) {  // diagonal tile: causal mask
#pragma unroll
      for (int nf=0;nf<4;nf++)
#pragma unroll
        for (int r=0;r<4;r++) {
          int qi = qt*64 + wid*16 + orow + r;
          int kj = kv0 + nf*16 + rla;
          if (kj > qi) sf[nf][r] = -INFINITY;
        }
    }
    // online softmax (row stats live in the 16 lanes of each col-group)
#pragma unroll
    for (int r=0;r<4;r++) {
      float mx = fmaxf(fmaxf(sf[0][r], sf[1][r]), fmaxf(sf[2][r], sf[3][r]));
#pragma unroll
      for (int m=1;m<16;m<<=1) mx = fmaxf(mx, __shfl_xor(mx, m));
      float mn = fmaxf(mrow[r], mx);
      float sc = __expf(mrow[r] - mn);   // first tile: exp(-inf)=0
      mrow[r] = mn;
      float ps = 0.f;
#pragma unroll
      for (int nf=0;nf<4;nf++) {
        float p = __expf(sf[nf][r] - mn);
        sf[nf][r] = p;
        ps += p;
      }
#pragma unroll
      for (int m=1;m<16;m<<=1) ps += __shfl_xor(ps, m);
      lrow[r] = lrow[r]*sc + ps;
#pragma unroll
      for (int df=0;df<4;df++) o[df][r] *= sc;
    }
    // write P (hi/lo) to per-wave LDS
#pragma unroll
    for (int nf=0;nf<4;nf++)
#pragma unroll
      for (int r=0;r<4;r++) {
        bf16 h_, l_;
        split2(sf[nf][r], h_, l_);
        Phi[wid][orow+r][nf*16+rla] = h_;
        Plo[wid][orow+r][nf*16+rla] = l_;
      }
    asm volatile("s_waitcnt lgkmcnt(0)" ::: "memory");
    __builtin_amdgcn_sched_barrier(0);
    // O += P V
    bf16x8 ph[2], pl[2];
    ph[0] = *(const bf16x8*)&Phi[wid][rla][kof];
    pl[0] = *(const bf16x8*)&Plo[wid][rla][kof];
    ph[1] = *(const bf16x8*)&Phi[wid][rla][32+kof];
    pl[1] = *(const bf16x8*)&Plo[wid][rla][32+kof];
#pragma unroll
    for (int df=0;df<4;df++) {
      f32x4 a = o[df];
#pragma unroll
      for (int k2=0;k2<2;k2++) {
        bf16x8 vh = *(const bf16x8*)&Vhi[df*16+rla][k2*32+kof];
        bf16x8 vl = *(const bf16x8*)&Vlo[df*16+rla][k2*32+kof];
        a = MFMA16(ph[k2], vh, a);
        a = MFMA16(ph[k2], vl, a);
        a = MFMA16(pl[k2], vh, a);
      }
      o[df] = a;
    }
    __syncthreads();
  }

  float inv[4];
#pragma unroll
  for (int r=0;r<4;r++) inv[r] = 1.0f / lrow[r];
#pragma unroll
  for (int df=0;df<4;df++)
#pragma unroll
    for (int r=0;r<4;r++) {
      int row = qt*64 + wid*16 + orow + r;
      int d   = h*HDd + df*16 + rla;
      size_t off = (size_t)(b*Tt + row)*Dd + d;
      float v = o[df][r] * inv[r];
      bf16 hh, ll; split2(v, hh, ll);
      yhi[off] = hh; ylo[off] = ll;
    }
}

// ---------------- loss ----------------
__global__ void k_loss_row(const float* __restrict__ logits, const int* __restrict__ tgt,
                           float* __restrict__ nll) {
  int row = blockIdx.x;
  const float* lr = logits + (size_t)row*Vv;
  int tid = threadIdx.x, wid = tid>>6, lane = tid&63;
  float s = 0.f;
  for (int c=tid; c<Vv; c+=256) s += __expf(lr[c]);
#pragma unroll
  for (int m=1;m<64;m<<=1) s += __shfl_xor(s, m);
  __shared__ float red[4];
  if (lane==0) red[wid]=s;
  __syncthreads();
  if (tid==0) {
    float tot = red[0]+red[1]+red[2]+red[3];
    nll[row] = logf(tot) - lr[tgt[row]];
  }
}

__global__ void k_loss_final(const float* __restrict__ nll, float* __restrict__ out) {
  int tid = threadIdx.x, wid = tid>>6, lane = tid&63;
  float s = 0.f;
  for (int i=tid; i<Mm; i+=256) s += nll[i];
#pragma unroll
  for (int m=1;m<64;m<<=1) s += __shfl_xor(s, m);
  __shared__ float red[4];
  if (lane==0) red[wid]=s;
  __syncthreads();
  if (tid==0) out[0] = (red[0]+red[1]+red[2]+red[3]) * (1.0f/Mm);
}

// ---------------- launch ----------------
extern "C" void kernel_launch(void* const* d_in, const int* in_sizes, int n_in,
                              void* d_out, int out_size, void* d_ws, size_t ws_size,
                              hipStream_t stream) {
  const int*   idx   = (const int*)  d_in[0];
  const int*   tgt   = (const int*)  d_in[1];
  const float* wte   = (const float*)d_in[2];
  const float* wpe   = (const float*)d_in[3];
  const float* ln1g  = (const float*)d_in[4];
  const float* ln1b  = (const float*)d_in[5];
  const float* wattn = (const float*)d_in[6];
  const float* wproj = (const float*)d_in[7];
  const float* ln2g  = (const float*)d_in[8];
  const float* ln2b  = (const float*)d_in[9];
  const float* wfc   = (const float*)d_in[10];
  const float* bfc   = (const float*)d_in[11];
  const float* wout  = (const float*)d_in[12];
  const float* bout  = (const float*)d_in[13];
  const float* lnfg  = (const float*)d_in[14];
  const float* lnfb  = (const float*)d_in[15];
  const float* whead = (const float*)d_in[16];
  float* out = (float*)d_out;

  char* wsp = (char*)d_ws;
  size_t off = 0;
  auto alloc = [&](size_t bytes) -> void* {
    void* p = wsp + off;
    off += (bytes + 255) & ~(size_t)255;
    return p;
  };
  float* x     = (float*)alloc((size_t)Mm*Dd*4);
  bf16*  hhi   = (bf16*) alloc((size_t)Mm*Dd*2);
  bf16*  hlo   = (bf16*) alloc((size_t)Mm*Dd*2);
  float* qkvb  = (float*)alloc((size_t)Mm*3*Dd*4);
  bf16*  yhi   = (bf16*) alloc((size_t)Mm*Dd*2);
  bf16*  ylo   = (bf16*) alloc((size_t)Mm*Dd*2);
  bf16*  fchi  = (bf16*) alloc((size_t)Mm*4*Dd*2);
  bf16*  fclo  = (bf16*) alloc((size_t)Mm*4*Dd*2);
  float* nllb  = (float*)alloc((size_t)Mm*4);
  bf16*  waT_h = (bf16*) alloc((size_t)Ll*Dd*3*Dd*2);
  bf16*  waT_l = (bf16*) alloc((size_t)Ll*Dd*3*Dd*2);
  bf16*  wpT_h = (bf16*) alloc((size_t)Ll*Dd*Dd*2);
  bf16*  wpT_l = (bf16*) alloc((size_t)Ll*Dd*Dd*2);
  bf16*  wfT_h = (bf16*) alloc((size_t)Ll*Dd*4*Dd*2);
  bf16*  wfT_l = (bf16*) alloc((size_t)Ll*Dd*4*Dd*2);
  bf16*  woT_h = (bf16*) alloc((size_t)Ll*4*Dd*Dd*2);
  bf16*  woT_l = (bf16*) alloc((size_t)Ll*4*Dd*Dd*2);
  bf16*  whT_h = (bf16*) alloc((size_t)Dd*Vv*2);
  bf16*  whT_l = (bf16*) alloc((size_t)Dd*Vv*2);
  if (off > ws_size) return;  // ws too small: leave output poisoned (loud failure)

  k_embed<<<Mm, 192, 0, stream>>>(idx, wte, wpe, x);

  dim3 tb(32, 8);
  k_wsplit<<<dim3(Dd/32, 3*Dd/32, Ll), tb, 0, stream>>>(wattn, waT_h, waT_l, Dd, 3*Dd);
  k_wsplit<<<dim3(Dd/32, Dd/32,   Ll), tb, 0, stream>>>(wproj, wpT_h, wpT_l, Dd, Dd);
  k_wsplit<<<dim3(Dd/32, 4*Dd/32, Ll), tb, 0, stream>>>(wfc,   wfT_h, wfT_l, Dd, 4*Dd);
  k_wsplit<<<dim3(4*Dd/32, Dd/32, Ll), tb, 0, stream>>>(wout,  woT_h, woT_l, 4*Dd, Dd);
  k_wsplit<<<dim3(Dd/32, Vv/32,    1), tb, 0, stream>>>(whead, whT_h, whT_l, Dd, Vv);

  for (int l = 0; l < Ll; l++) {
    size_t wa = (size_t)l*Dd*3*Dd, wp = (size_t)l*Dd*Dd, wf = (size_t)l*Dd*4*Dd;
    k_ln<<<Mm, 256, 0, stream>>>(x, ln1g + l*Dd, ln1b + l*Dd, hhi, hlo);
    k_gemm<0><<<dim3(Mm/128, 3*Dd/128), 256, 0, stream>>>(
        hhi, hlo, waT_h+wa, waT_l+wa, Dd, 3*Dd, qkvb, nullptr, nullptr, nullptr, nullptr);
    k_attn<<<dim3(Tt/64, Hh, Bb), 256, 0, stream>>>(qkvb, yhi, ylo);
    k_gemm<1><<<dim3(Mm/128, Dd/128), 256, 0, stream>>>(
        yhi, ylo, wpT_h+wp, wpT_l+wp, Dd, Dd, x, x, nullptr, nullptr, nullptr);
    k_ln<<<Mm, 256, 0, stream>>>(x, ln2g + l*Dd, ln2b + l*Dd, hhi, hlo);
    k_gemm<2><<<dim3(Mm/128, 4*Dd/128), 256, 0, stream>>>(
        hhi, hlo, wfT_h+wf, wfT_l+wf, Dd, 4*Dd, nullptr, nullptr,
        bfc + (size_t)l*4*Dd, fchi, fclo);
    k_gemm<3><<<dim3(Mm/128, Dd/128), 256, 0, stream>>>(
        fchi, fclo, woT_h+wf, woT_l+wf, 4*Dd, Dd, x, x,
        bout + (size_t)l*Dd, nullptr, nullptr);
  }

  k_ln<<<Mm, 256, 0, stream>>>(x, lnfg, lnfb, hhi, hlo);
  k_gemm<0><<<dim3(Mm/128, Vv/128), 256, 0, stream>>>(
      hhi, hlo, whT_h, whT_l, Dd, Vv, out, nullptr, nullptr, nullptr, nullptr);
  k_loss_row<<<Mm, 256, 0, stream>>>(out, tgt, nllb);
  k_loss_final<<<1, 256, 0, stream>>>(nllb, out + (size_t)Mm*Vv);
}